// Round 8
// baseline (78.304 us; speedup 1.0000x reference)
//
#include <hip/hip_runtime.h>

typedef float f32x4 __attribute__((ext_vector_type(4)));
typedef short s16x8 __attribute__((ext_vector_type(8)));

// software f32->bf16 RNE (proven R3-R5)
__device__ __forceinline__ ushort f2bf(float f) {
  unsigned u = __float_as_uint(f);
  unsigned r = (u + 0x7fffu + ((u >> 16) & 1u)) >> 16;
  return (ushort)r;
}
__device__ __forceinline__ uint pk2(float a, float b) {
  return (uint)f2bf(a) | ((uint)f2bf(b) << 16);
}

// ---- conv1 A-fragment: 8 contiguous pixels of one row, boundary-masked ----
__device__ __forceinline__ s16x8 loadA(const float2* __restrict__ x2, int cb2,
                                       int c, int ky, int oy, int ox) {
  int iy = 4 * oy - 2 + ky;
  uint rm = ((unsigned)iy < 48u) ? 0xFFFFFFFFu : 0u;
  int iyc = iy < 0 ? 0 : (iy > 47 ? 47 : iy);
  const float2* row = x2 + (cb2 + c * 73728 + iyc * 192 + 2 * ox - 1);
  bool e0 = (ox == 0), e3 = (ox == 11);       // fully-invalid end chunks
  float2 c0 = row[e0 ? 1 : 0];                // clamp addr (value masked)
  float2 c1 = row[1];
  float2 c2 = row[2];
  float2 c3 = row[e3 ? 2 : 3];                // clamp addr (value masked)
  uint m0 = e0 ? 0u : rm, m3 = e3 ? 0u : rm;
  s16x8 a;
  ((uint*)&a)[0] = pk2(c0.x, c0.y) & m0;
  ((uint*)&a)[1] = pk2(c1.x, c1.y) & rm;
  ((uint*)&a)[2] = pk2(c2.x, c2.y) & rm;
  ((uint*)&a)[3] = pk2(c3.x, c3.y) & m3;
  return a;
}

// ---- conv1 epilogue: bias+relu, scatter into conv2 im2col (LDS) ----
__device__ __forceinline__ void epi1(ushort* A2, f32x4 acc, int mt, int r16,
                                     int g, float b1v) {
#pragma unroll
  for (int rr = 0; rr < 4; ++rr) {
    int m = mt * 16 + g * 4 + rr;
    int oy = m / 12, ox = m - 12 * oy;
    if (oy < 11 && ox < 11) {
      float v = fmaxf(acc[rr] + b1v, 0.f);
      int py = (oy + 1) >> 2, k2y = (oy + 1) & 3;
      int px = (ox + 1) >> 2, k2x = (ox + 1) & 3;
      A2[(py * 3 + px) * 264 + r16 * 16 + k2y * 4 + k2x] = f2bf(v);
    }
  }
}

// ================= Kernel A: conv1 + conv2, one cell per block =============
__global__ __launch_bounds__(256, 6)
void conv_kernel(const float* __restrict__ x,
                 const float* __restrict__ w1, const float* __restrict__ b1,
                 const float* __restrict__ w2, const float* __restrict__ b2,
                 ushort* __restrict__ h2g)
{
  __shared__ __align__(16) ushort A2[16 * 264];   // 8448 B im2col for conv2

  const int t = threadIdx.x;
  const int w = t >> 6;
  const int r16 = t & 15;
  const int g = (t & 63) >> 4;
  const int cell = blockIdx.x;

  // zero A2 (rows 9..15 and pad slots stay 0)
  for (int i = t; i < 2112; i += 256) ((uint*)A2)[i] = 0u;
  __syncthreads();                               // zero visible before epi1 scatter

  const int b = cell >> 6, gg = cell & 63;
  const int cb2 = b * 221184 + (gg >> 3) * 9216 + (gg & 7) * 24;  // float2 units
  const float2* x2 = (const float2*)x;

  // wave w owns m-tiles {w, w+4}, wave 2 additionally tile 8
  const int mt0 = w, mt1 = w + 4;
  int m0 = mt0 * 16 + r16, m1 = mt1 * 16 + r16, m2_ = 128 + r16;
  const int oy0 = m0 / 12, ox0 = m0 - 12 * oy0;
  const int oy1 = m1 / 12, ox1 = m1 - 12 * oy1;
  const int oy2 = m2_ / 12, ox2 = m2_ - 12 * oy2;

  f32x4 a0 = (f32x4){0.f, 0.f, 0.f, 0.f};
  f32x4 a1 = (f32x4){0.f, 0.f, 0.f, 0.f};
  f32x4 a2 = (f32x4){0.f, 0.f, 0.f, 0.f};

#pragma unroll
  for (int s = 0; s < 6; ++s) {
    // B-fragment: w1[oc=r16][k=32s+8g .. +7] fp32 -> bf16
    const float2* wp = (const float2*)(w1 + r16 * 192 + s * 32 + g * 8);
    float2 q0 = wp[0], q1 = wp[1], q2 = wp[2], q3 = wp[3];
    s16x8 bf;
    ((uint*)&bf)[0] = pk2(q0.x, q0.y);
    ((uint*)&bf)[1] = pk2(q1.x, q1.y);
    ((uint*)&bf)[2] = pk2(q2.x, q2.y);
    ((uint*)&bf)[3] = pk2(q3.x, q3.y);
    int c = s >> 1;
    int ky = (s & 1) * 4 + g;
    a0 = __builtin_amdgcn_mfma_f32_16x16x32_bf16(loadA(x2, cb2, c, ky, oy0, ox0), bf, a0, 0, 0, 0);
    a1 = __builtin_amdgcn_mfma_f32_16x16x32_bf16(loadA(x2, cb2, c, ky, oy1, ox1), bf, a1, 0, 0, 0);
    if (w == 2)
      a2 = __builtin_amdgcn_mfma_f32_16x16x32_bf16(loadA(x2, cb2, c, ky, oy2, ox2), bf, a2, 0, 0, 0);
  }

  const float b1v = b1[r16];
  epi1(A2, a0, mt0, r16, g, b1v);
  epi1(A2, a1, mt1, r16, g, b1v);
  if (w == 2) epi1(A2, a2, 8, r16, g, b1v);

  __syncthreads();

  // ---- conv2: M=9(pad16), N=32 -> waves 0,1 (one 16-wide n-tile each), K=256
  if (w < 2) {
    const float b2v = b2[w * 16 + r16];
    f32x4 c2acc = (f32x4){0.f, 0.f, 0.f, 0.f};
    const float2* w2p = (const float2*)(w2 + (w * 16 + r16) * 256 + g * 8);
#pragma unroll
    for (int s2 = 0; s2 < 8; ++s2) {
      uint4 av = *(const uint4*)&A2[r16 * 264 + s2 * 32 + g * 8];
      float2 q0 = w2p[s2 * 16 + 0], q1 = w2p[s2 * 16 + 1],
             q2 = w2p[s2 * 16 + 2], q3 = w2p[s2 * 16 + 3];
      s16x8 bf;
      ((uint*)&bf)[0] = pk2(q0.x, q0.y);
      ((uint*)&bf)[1] = pk2(q1.x, q1.y);
      ((uint*)&bf)[2] = pk2(q2.x, q2.y);
      ((uint*)&bf)[3] = pk2(q3.x, q3.y);
      c2acc = __builtin_amdgcn_mfma_f32_16x16x32_bf16(*(s16x8*)&av, bf, c2acc, 0, 0, 0);
    }
#pragma unroll
    for (int rr = 0; rr < 4; ++rr) {
      int p2 = g * 4 + rr;
      if (p2 < 9) {
        float v = fmaxf(c2acc[rr] + b2v, 0.f);
        h2g[cell * 288 + (w * 16 + r16) * 9 + p2] = f2bf(v);
      }
    }
  }
}

// ============ Kernel B: fc1(MFMA) + fc2 + softmax, 16 cells per block ======
__global__ __launch_bounds__(256, 4)
void fc_kernel(const float* __restrict__ fw1, const float* __restrict__ fb1,
               const float* __restrict__ fw2, const float* __restrict__ fb2,
               const ushort* __restrict__ h2g, float* __restrict__ out)
{
  __shared__ __align__(16) ushort h2s[16 * 296];
  __shared__ __align__(16) float h3s[16 * 260];
  __shared__ float ls[16][4];

  const int t = threadIdx.x;
  const int w = t >> 6;
  const int r16 = t & 15;
  const int g = (t & 63) >> 4;
  const int c0 = blockIdx.x * 16;

  // load h2 for 16 cells (coalesced uint), pad stride 296
  // 16 cells x 288 ushorts = 2304 uints (R7 bug: was 1152 -> cells 8..15 garbage)
  const uint* src = (const uint*)(h2g + c0 * 288);
  for (int j = t; j < 2304; j += 256) {
    int r = j / 144, ci = j - r * 144;
    *(uint*)&h2s[r * 296 + 2 * ci] = src[j];
  }
  __syncthreads();

  // ---- fc1 MFMA: M=16 cells, N=256 (wave w -> n-tiles 4w..4w+3), K=288 ----
  s16x8 af[9];
#pragma unroll
  for (int s = 0; s < 9; ++s)
    af[s] = *(const s16x8*)&h2s[r16 * 296 + s * 32 + g * 8];

  f32x4 fa0 = (f32x4){0.f,0.f,0.f,0.f}, fa1 = fa0, fa2 = fa0, fa3 = fa0;
#pragma unroll
  for (int s = 0; s < 9; ++s) {
    const int ko = s * 32 + g * 8;
#pragma unroll
    for (int i = 0; i < 4; ++i) {
      const float2* p = (const float2*)(fw1 + ((w * 4 + i) * 16 + r16) * 288 + ko);
      float2 q0 = p[0], q1 = p[1], q2 = p[2], q3 = p[3];
      s16x8 bf;
      ((uint*)&bf)[0] = pk2(q0.x, q0.y);
      ((uint*)&bf)[1] = pk2(q1.x, q1.y);
      ((uint*)&bf)[2] = pk2(q2.x, q2.y);
      ((uint*)&bf)[3] = pk2(q3.x, q3.y);
      if (i == 0) fa0 = __builtin_amdgcn_mfma_f32_16x16x32_bf16(af[s], bf, fa0, 0, 0, 0);
      if (i == 1) fa1 = __builtin_amdgcn_mfma_f32_16x16x32_bf16(af[s], bf, fa1, 0, 0, 0);
      if (i == 2) fa2 = __builtin_amdgcn_mfma_f32_16x16x32_bf16(af[s], bf, fa2, 0, 0, 0);
      if (i == 3) fa3 = __builtin_amdgcn_mfma_f32_16x16x32_bf16(af[s], bf, fa3, 0, 0, 0);
    }
  }
#pragma unroll
  for (int i = 0; i < 4; ++i) {
    f32x4 fa = (i == 0) ? fa0 : (i == 1) ? fa1 : (i == 2) ? fa2 : fa3;
    int n = (w * 4 + i) * 16 + r16;
    float fb = fb1[n];
#pragma unroll
    for (int rr = 0; rr < 4; ++rr)
      h3s[(g * 4 + rr) * 260 + n] = fmaxf(fa[rr] + fb, 0.f);
  }
  __syncthreads();

  // ---- fc2: 64 units (16 cells x 4 logits) x 4 lanes ----
  {
    int u = t >> 2, sub = t & 3;
    int cl = u >> 2, j = u & 3;
    const float4* hp = (const float4*)&h3s[cl * 260];
    const float4* wp = (const float4*)(fw2 + j * 256);
    float p = 0.f;
#pragma unroll
    for (int i = 0; i < 16; ++i) {
      int k4 = sub + 4 * i;
      float4 a = hp[k4], bb = wp[k4];
      p = fmaf(a.x, bb.x, p); p = fmaf(a.y, bb.y, p);
      p = fmaf(a.z, bb.z, p); p = fmaf(a.w, bb.w, p);
    }
    p += __shfl_xor(p, 1);
    p += __shfl_xor(p, 2);
    if (sub == 0) ls[cl][j] = p + fb2[j];
  }
  __syncthreads();

  // ---- softmax + store ----
  if (t < 16) {
    float l0 = ls[t][0], l1 = ls[t][1], l2 = ls[t][2], l3 = ls[t][3];
    float m = fmaxf(fmaxf(l0, l1), fmaxf(l2, l3));
    float e0 = __expf(l0 - m), e1 = __expf(l1 - m),
          e2 = __expf(l2 - m), e3 = __expf(l3 - m);
    float inv = 1.f / (e0 + e1 + e2 + e3);
    int n = c0 + t;
    out[n] = e0 * inv;
    out[4096 + n] = e1 * inv;
    out[8192 + n] = e2 * inv;
  }
}

extern "C" void kernel_launch(void* const* d_in, const int* in_sizes, int n_in,
                              void* d_out, int out_size, void* d_ws, size_t ws_size,
                              hipStream_t stream) {
  const float* x   = (const float*)d_in[0];
  const float* w1  = (const float*)d_in[1];
  const float* b1  = (const float*)d_in[2];
  const float* w2  = (const float*)d_in[3];
  const float* b2  = (const float*)d_in[4];
  const float* fw1 = (const float*)d_in[5];
  const float* fb1 = (const float*)d_in[6];
  const float* fw2 = (const float*)d_in[7];
  const float* fb2 = (const float*)d_in[8];
  float* out = (float*)d_out;
  ushort* h2g = (ushort*)d_ws;   // 4096*288*2 = 2,359,296 B conv2 output (bf16)

  hipLaunchKernelGGL(conv_kernel, dim3(4096), dim3(256), 0, stream,
                     x, w1, b1, w2, b2, h2g);
  hipLaunchKernelGGL(fc_kernel, dim3(256), dim3(256), 0, stream,
                     fw1, fb1, fw2, fb2, h2g, out);
}